// Round 8
// baseline (129.837 us; speedup 1.0000x reference)
//
#include <hip/hip_runtime.h>

#define NB 8
#define NT 512
#define NS 512
#define NH 128
#define C2LOG2E 2.8853900817779268f   // 2*log2(e): exp2(C*x) = e^(2x)

__device__ __forceinline__ float fast_exp2(float x) { return __builtin_amdgcn_exp2f(x); }
__device__ __forceinline__ float fast_rcp(float x)  { return __builtin_amdgcn_rcpf(x); }
__device__ __forceinline__ float fast_tanh(float x) {
  float e = fast_exp2(x * C2LOG2E);
  return 1.0f - 2.0f * fast_rcp(e + 1.0f);
}

__device__ __forceinline__ float dot4(float4 a, float4 b) {
  return (a.x * b.x + a.y * b.y) + (a.z * b.z + a.w * b.w);
}

// acc += v0/(e0*f0+1) + v1/(e1*f1+1) over a float4 of s; 1 rcp / 2 h-elems.
__device__ __forceinline__ float4 pair_acc(float e0, float e1, float v0, float v1,
                                           float4 f0, float4 f1, float4 acc) {
  float4 P0, P1, num, den;
  P0.x = fmaf(e0, f0.x, 1.0f); P0.y = fmaf(e0, f0.y, 1.0f);
  P0.z = fmaf(e0, f0.z, 1.0f); P0.w = fmaf(e0, f0.w, 1.0f);
  P1.x = fmaf(e1, f1.x, 1.0f); P1.y = fmaf(e1, f1.y, 1.0f);
  P1.z = fmaf(e1, f1.z, 1.0f); P1.w = fmaf(e1, f1.w, 1.0f);
  num.x = fmaf(v0, P1.x, v1 * P0.x); num.y = fmaf(v0, P1.y, v1 * P0.y);
  num.z = fmaf(v0, P1.z, v1 * P0.z); num.w = fmaf(v0, P1.w, v1 * P0.w);
  den.x = P0.x * P1.x; den.y = P0.y * P1.y;
  den.z = P0.z * P1.z; den.w = P0.w * P1.w;
  acc.x = fmaf(num.x, fast_rcp(den.x), acc.x);
  acc.y = fmaf(num.y, fast_rcp(den.y), acc.y);
  acc.z = fmaf(num.z, fast_rcp(den.z), acc.z);
  acc.w = fmaf(num.w, fast_rcp(den.w), acc.w);
  return acc;
}

// ---------------- K1: four 4096x128x128 GEMMs (round-7, proven) -----------
// set 0: EWS  = exp2(C*(q  @ W_s^T))            [b][t][h]
// set 1: EWHT = exp2(C*(enc@ W_h^T)) TRANSPOSED [b][h][s]
// set 2: ENCW = enc @ W1^T   (W1 = Wout[:, :128])        [b][s][c]
// set 3: QW2  = q @ W2^T + b (W2 = Wout[:, 128:])        [b][t][c]
__global__ __launch_bounds__(256) void bah_proj_kernel(
    const float* __restrict__ query, const float* __restrict__ enc,
    const float* __restrict__ W_s, const float* __restrict__ W_h,
    const float* __restrict__ Wout, const float* __restrict__ Woutb,
    float* __restrict__ EWS, float* __restrict__ EWHT,
    float* __restrict__ ENCW, float* __restrict__ QW2) {
  __shared__ __align__(16) float lds_w[64 * 132];   // 33.8 KB: one col-half
  __shared__ __align__(16) float lds_x[32 * 132];   // 16.9 KB; reused 64x33
  const int set = blockIdx.x >> 8;
  const int blk = blockIdx.x & 255;
  const int rb = blk >> 1, ch = blk & 1;
  const int r0 = rb * 32, c0 = ch * 64;
  const int tid = threadIdx.x;
  const float* in = (set == 1 || set == 2) ? enc : query;
  const float* Wb; int wst;
  if (set == 0)      { Wb = W_s;        wst = 128; }
  else if (set == 1) { Wb = W_h;        wst = 128; }
  else if (set == 2) { Wb = Wout;       wst = 256; }
  else               { Wb = Wout + 128; wst = 256; }
  for (int i = tid; i < 2048; i += 256) {           // W: 64 rows x 32 float4
    int r = i >> 5, c4 = i & 31;
    *(float4*)(lds_w + r * 132 + c4 * 4) =
        *(const float4*)(Wb + (c0 + r) * wst + c4 * 4);
  }
  for (int i = tid; i < 1024; i += 256) {           // x: 32 rows x 32 float4
    int r = i >> 5, c4 = i & 31;
    *(float4*)(lds_x + r * 132 + c4 * 4) =
        *(const float4*)(in + (r0 + r) * NH + c4 * 4);
  }
  __syncthreads();
  const int cg = tid & 31;         // cols c0+cg, c0+cg+32
  const int rg = tid >> 5;         // rows rg*4 .. rg*4+3
  float acc[4][2] = {{0,0},{0,0},{0,0},{0,0}};
  for (int k4 = 0; k4 < 32; ++k4) {
    float4 xa[4], wb[2];
    #pragma unroll
    for (int i = 0; i < 4; ++i)      // wave-uniform addr -> broadcast
      xa[i] = *(const float4*)(lds_x + (rg * 4 + i) * 132 + k4 * 4);
    #pragma unroll
    for (int m = 0; m < 2; ++m)      // bank = (cg+k4)%32 -> conflict-free
      wb[m] = *(const float4*)(lds_w + (cg + 32 * m) * 132 + k4 * 4);
    #pragma unroll
    for (int i = 0; i < 4; ++i)
      #pragma unroll
      for (int m = 0; m < 2; ++m)
        acc[i][m] += dot4(xa[i], wb[m]);
  }
  if (set == 0) {
    #pragma unroll
    for (int i = 0; i < 4; ++i)
      #pragma unroll
      for (int m = 0; m < 2; ++m)    // lanes cg consecutive -> coalesced
        EWS[(r0 + rg * 4 + i) * NH + c0 + cg + 32 * m] =
            fast_exp2(C2LOG2E * acc[i][m]);
  } else if (set == 1) {
    __syncthreads();                 // lds_x dead; reuse as 64x33 transpose
    #pragma unroll
    for (int i = 0; i < 4; ++i)
      #pragma unroll
      for (int m = 0; m < 2; ++m)
        lds_x[(cg + 32 * m) * 33 + rg * 4 + i] = fast_exp2(C2LOG2E * acc[i][m]);
    __syncthreads();
    const int b = r0 >> 9, sl0 = r0 & 511;
    const int s_lane = tid & 31, hr = tid >> 5;   // 8 groups x 8 h-rows
    #pragma unroll
    for (int j = 0; j < 8; ++j)      // lanes s consecutive -> coalesced 128B
      EWHT[b * NH * NS + (c0 + hr * 8 + j) * NS + sl0 + s_lane] =
          lds_x[(hr * 8 + j) * 33 + s_lane];
  } else if (set == 2) {
    #pragma unroll
    for (int i = 0; i < 4; ++i)
      #pragma unroll
      for (int m = 0; m < 2; ++m)
        ENCW[(r0 + rg * 4 + i) * NH + c0 + cg + 32 * m] = acc[i][m];
  } else {
    #pragma unroll
    for (int i = 0; i < 4; ++i)
      #pragma unroll
      for (int m = 0; m < 2; ++m) {
        int c = c0 + cg + 32 * m;    // bias folded here, not in mega
        QW2[(r0 + rg * 4 + i) * NH + c] = acc[i][m] + Woutb[c];
      }
  }
}

// -------- K2: MEGA v2 — 256 thr, 4 t-rows, grid 1024, ~20 KB LDS ----------
// 4 blocks/CU x 4 waves = 16 waves/CU; small blocks let phases interleave.
// Phase B: thread owns 4 s (float4 F) x 4 t x 64 h -> 1 B LDS per element.
__global__ __launch_bounds__(256, 4) void bah_mega_kernel(
    const float* __restrict__ EWS, const float* __restrict__ EWHT,
    const float* __restrict__ v, const float* __restrict__ ENCW,
    const float* __restrict__ QW2, const int* __restrict__ src_len,
    float* __restrict__ out) {
  // Arena (floats), phase-aliased:
  //  A [0,2176)     s_par (B: 128x17) -> s_aT (C,D: 512x4 = 2048)
  //  B [2176,4240)  s_sc (B,C: 4x516) -> lred (D: 4x512 = 2048)
  //  C [4240,4768)  s_et (B: 4x132)
  //  D [4768,4896)  s_v
  //  E [4896,4928)  s_red
  __shared__ __align__(16) float smem[4928];
  float* s_aT  = smem;            // also s_par
  float* s_par = smem;
  float* s_sc  = smem + 2176;
  float* lred  = smem + 2176;
  float* s_et  = smem + 4240;
  float* s_v   = smem + 4768;
  float* s_red = smem + 4896;

  const int tid = threadIdx.x;
  const int bb = blockIdx.x >> 7;
  const int t0 = (blockIdx.x & 127) * 4;
  const int len = src_len[bb];

  if (tid < 32) *(float4*)(s_v + tid * 4) = *(const float4*)(v + tid * 4);
  if (tid < 128) {                     // 4x128 EWS rows = 128 float4
    int r = tid >> 5, c4 = tid & 31;
    *(float4*)(s_et + r * 132 + c4 * 4) =
        *(const float4*)(EWS + (bb * NT + t0 + r) * NH + c4 * 4);
  }
  __syncthreads();

  // V0 = sum(v): one float2 + wave shuffles
  float V0;
  {
    float2 vv = *(const float2*)(s_v + (tid & 63) * 2);
    V0 = vv.x + vv.y;
    #pragma unroll
    for (int msk = 1; msk <= 32; msk <<= 1)
      V0 += __shfl_xor(V0, msk, 64);
  }

  // ---- Phase B: tg=tid>>7 (h-half), sp=tid&127 (4 contiguous s), 4 t ----
  const int tg = tid >> 7, sp = tid & 127;
  const int sbase = sp * 4;
  const int h0 = tg * 64;
  float4 acc4[4] = {{0,0,0,0},{0,0,0,0},{0,0,0,0},{0,0,0,0}};
  const int wave_s0 = (sp & 64) * 4;      // wave-uniform: 0 or 256
  if (wave_s0 < len) {                    // skip fully-masked s-span
    const float* fb = EWHT + bb * NH * NS + h0 * NS + sbase;
    for (int ho = 0; ho < 8; ++ho) {
      const float* fh = fb + ho * 8 * NS;
      float4 F0 = *(const float4*)(fh + 0 * NS);   // coalesced 16B/lane (L2)
      float4 F1 = *(const float4*)(fh + 1 * NS);
      float4 F2 = *(const float4*)(fh + 2 * NS);
      float4 F3 = *(const float4*)(fh + 3 * NS);
      float4 F4 = *(const float4*)(fh + 4 * NS);
      float4 F5 = *(const float4*)(fh + 5 * NS);
      float4 F6 = *(const float4*)(fh + 6 * NS);
      float4 F7 = *(const float4*)(fh + 7 * NS);
      float4 va = *(const float4*)(s_v + h0 + ho * 8);
      float4 vb = *(const float4*)(s_v + h0 + ho * 8 + 4);
      #pragma unroll
      for (int tt = 0; tt < 4; ++tt) {
        float4 e0 = *(const float4*)(s_et + tt * 132 + h0 + ho * 8);  // bcast
        float4 e1 = *(const float4*)(s_et + tt * 132 + h0 + ho * 8 + 4);
        acc4[tt] = pair_acc(e0.x, e0.y, va.x, va.y, F0, F1, acc4[tt]);
        acc4[tt] = pair_acc(e0.z, e0.w, va.z, va.w, F2, F3, acc4[tt]);
        acc4[tt] = pair_acc(e1.x, e1.y, vb.x, vb.y, F4, F5, acc4[tt]);
        acc4[tt] = pair_acc(e1.z, e1.w, vb.z, vb.w, F6, F7, acc4[tt]);
      }
    }
  }
  if (tg == 1) {                       // stride 17: gcd(17,32)=1 -> ok
    #pragma unroll
    for (int tt = 0; tt < 4; ++tt)
      *(float4*)(s_par + sp * 17 + tt * 4) = acc4[tt];
  }
  __syncthreads();
  if (tg == 0) {
    #pragma unroll
    for (int tt = 0; tt < 4; ++tt) {
      float4 oth = *(const float4*)(s_par + sp * 17 + tt * 4);
      float4 r;  // faithful quirk: masked scores ZEROED, still in softmax
      r.x = (sbase + 0 < len) ? fmaf(-2.f, acc4[tt].x + oth.x, V0) : 0.f;
      r.y = (sbase + 1 < len) ? fmaf(-2.f, acc4[tt].y + oth.y, V0) : 0.f;
      r.z = (sbase + 2 < len) ? fmaf(-2.f, acc4[tt].z + oth.z, V0) : 0.f;
      r.w = (sbase + 3 < len) ? fmaf(-2.f, acc4[tt].w + oth.w, V0) : 0.f;
      *(float4*)(s_sc + tt * 516 + sbase) = r;
    }
  }
  __syncthreads();

  // ---- Phase C: softmax per t-row (4 rows); attn transposed into s_aT ----
  const int t = tid & 3;
  const int c = tid >> 2;       // 0..63, 8 strided s values each
  const int wv = tid >> 6;
  float pv[8];
  float mx = -3.4e38f;
  #pragma unroll
  for (int k = 0; k < 8; ++k) {
    pv[k] = s_sc[t * 516 + c + 64 * k];
    mx = fmaxf(mx, pv[k]);
  }
  #pragma unroll
  for (int msk = 4; msk <= 32; msk <<= 1)
    mx = fmaxf(mx, __shfl_xor(mx, msk, 64));
  if ((tid & 63) < 4) s_red[wv * 4 + t] = mx;
  __syncthreads();
  mx = fmaxf(fmaxf(s_red[t], s_red[4 + t]),
             fmaxf(s_red[8 + t], s_red[12 + t]));
  __syncthreads();              // reads done before s_red rewrite
  float sum = 0.f;
  #pragma unroll
  for (int k = 0; k < 8; ++k) {
    pv[k] = fast_exp2((pv[k] - mx) * 1.4426950408889634f);
    sum += pv[k];
  }
  #pragma unroll
  for (int msk = 4; msk <= 32; msk <<= 1)
    sum += __shfl_xor(sum, msk, 64);
  if ((tid & 63) < 4) s_red[wv * 4 + t] = sum;
  __syncthreads();
  sum = (s_red[t] + s_red[4 + t]) + (s_red[8 + t] + s_red[12 + t]);
  const float rd = fast_rcp(sum);
  // NOTE: s_aT overlays s_par (dead after B-combine). Write after sync above.
  #pragma unroll
  for (int k = 0; k < 8; ++k)   // word 4c+256k+t: consecutive per wave
    s_aT[(c + 64 * k) * 4 + t] = pv[k] * rd;
  __syncthreads();

  // ---- Phase D: pre_out[t][c] = sum_s attn[t][s]*ENCW[s][c]; +QW2; tanh --
  const int hg = tid & 31, sg = tid >> 5;   // 8 s-groups x 64 s
  float4 a4[4] = {{0,0,0,0},{0,0,0,0},{0,0,0,0},{0,0,0,0}};
  const float* eb = ENCW + bb * NS * NH + hg * 4;
  for (int k = 0; k < 64; ++k) {
    int s = sg * 64 + k;
    float4 e = *(const float4*)(eb + s * NH);       // coalesced global
    float4 w = *(const float4*)(s_aT + s * 4);      // 2 addrs/wave: free
    a4[0].x += w.x*e.x; a4[0].y += w.x*e.y; a4[0].z += w.x*e.z; a4[0].w += w.x*e.w;
    a4[1].x += w.y*e.x; a4[1].y += w.y*e.y; a4[1].z += w.y*e.z; a4[1].w += w.y*e.w;
    a4[2].x += w.z*e.x; a4[2].y += w.z*e.y; a4[2].z += w.z*e.z; a4[2].w += w.z*e.w;
    a4[3].x += w.w*e.x; a4[3].y += w.w*e.y; a4[3].z += w.w*e.z; a4[3].w += w.w*e.w;
  }
  #pragma unroll
  for (int i = 0; i < 4; ++i) {     // sg pairs within wave (lane^32)
    a4[i].x += __shfl_xor(a4[i].x, 32, 64);
    a4[i].y += __shfl_xor(a4[i].y, 32, 64);
    a4[i].z += __shfl_xor(a4[i].z, 32, 64);
    a4[i].w += __shfl_xor(a4[i].w, 32, 64);
  }
  if ((tid & 63) < 32) {            // lred overlays s_sc (dead after C)
    #pragma unroll
    for (int i = 0; i < 4; ++i)
      *(float4*)(lred + wv * 512 + i * 128 + hg * 4) = a4[i];
  }
  __syncthreads();
  if (tid < 128) {                  // final reduce + QW2 (has bias) + tanh
    int tt = tid >> 5, hh = tid & 31;
    float4 s0 = *(const float4*)(lred + 0 * 512 + tt * 128 + hh * 4);
    float4 s1 = *(const float4*)(lred + 1 * 512 + tt * 128 + hh * 4);
    float4 s2 = *(const float4*)(lred + 2 * 512 + tt * 128 + hh * 4);
    float4 s3 = *(const float4*)(lred + 3 * 512 + tt * 128 + hh * 4);
    const int row = bb * NT + t0 + tt;
    float4 q4 = *(const float4*)(QW2 + row * NH + hh * 4);  // coalesced
    float4 r;
    r.x = fast_tanh(((s0.x + s1.x) + (s2.x + s3.x)) + q4.x);
    r.y = fast_tanh(((s0.y + s1.y) + (s2.y + s3.y)) + q4.y);
    r.z = fast_tanh(((s0.z + s1.z) + (s2.z + s3.z)) + q4.z);
    r.w = fast_tanh(((s0.w + s1.w) + (s2.w + s3.w)) + q4.w);
    *(float4*)(out + row * NH + hh * 4) = r;
  }
}

extern "C" void kernel_launch(void* const* d_in, const int* in_sizes, int n_in,
                              void* d_out, int out_size, void* d_ws, size_t ws_size,
                              hipStream_t stream) {
  const float* query = (const float*)d_in[0];
  const float* enc   = (const float*)d_in[1];
  const int*   slen  = (const int*)d_in[2];
  const float* W_h   = (const float*)d_in[3];
  const float* W_s   = (const float*)d_in[4];
  const float* v     = (const float*)d_in[5];
  const float* Woutw = (const float*)d_in[6];
  const float* Woutb = (const float*)d_in[7];
  float* out = (float*)d_out;

  float* ws = (float*)d_ws;
  float* EWS  = ws;                  // B*T*H (2 MB)
  float* EWHT = ws + 524288;         // B*H*S transposed (2 MB)
  float* ENCW = ws + 1048576;        // B*S*H = enc @ W1^T (2 MB)
  float* QW2  = ws + 1572864;        // B*T*H = q @ W2^T + bias (2 MB)

  bah_proj_kernel<<<1024, 256, 0, stream>>>(query, enc, W_s, W_h, Woutw,
                                            Woutb, EWS, EWHT, ENCW, QW2);
  bah_mega_kernel<<<1024, 256, 0, stream>>>(EWS, EWHT, v, ENCW, QW2, slen, out);
}

// Round 9
// 126.541 us; speedup vs baseline: 1.0260x; 1.0260x over previous
//
#include <hip/hip_runtime.h>

#define NB 8
#define NT 512
#define NS 512
#define NH 128
#define C2LOG2E 2.8853900817779268f   // 2*log2(e): exp2(C*x) = e^(2x)

__device__ __forceinline__ float fast_exp2(float x) { return __builtin_amdgcn_exp2f(x); }
__device__ __forceinline__ float fast_rcp(float x)  { return __builtin_amdgcn_rcpf(x); }
__device__ __forceinline__ float fast_tanh(float x) {
  float e = fast_exp2(x * C2LOG2E);
  return 1.0f - 2.0f * fast_rcp(e + 1.0f);
}

__device__ __forceinline__ float dot4(float4 a, float4 b) {
  return (a.x * b.x + a.y * b.y) + (a.z * b.z + a.w * b.w);
}

// acc += v0/(e0*f0+1) + v1/(e1*f1+1) over 2 s values; 1 rcp per 2 h-elems.
__device__ __forceinline__ float2 pair_acc2(float e0, float e1, float v0, float v1,
                                            float2 f0, float2 f1, float2 acc) {
  float2 P0, P1, num, den;
  P0.x = fmaf(e0, f0.x, 1.0f); P0.y = fmaf(e0, f0.y, 1.0f);
  P1.x = fmaf(e1, f1.x, 1.0f); P1.y = fmaf(e1, f1.y, 1.0f);
  num.x = fmaf(v0, P1.x, v1 * P0.x); num.y = fmaf(v0, P1.y, v1 * P0.y);
  den.x = P0.x * P1.x; den.y = P0.y * P1.y;
  acc.x = fmaf(num.x, fast_rcp(den.x), acc.x);
  acc.y = fmaf(num.y, fast_rcp(den.y), acc.y);
  return acc;
}

// ---------------- K1: four 4096x128x128 GEMMs (round-7, proven) -----------
// set 0: EWS  = exp2(C*(q  @ W_s^T))            [b][t][h]
// set 1: EWHT = exp2(C*(enc@ W_h^T)) TRANSPOSED [b][h][s]
// set 2: ENCW = enc @ W1^T   (W1 = Wout[:, :128])        [b][s][c]
// set 3: QW2  = q @ W2^T + b (W2 = Wout[:, 128:])        [b][t][c]
__global__ __launch_bounds__(256) void bah_proj_kernel(
    const float* __restrict__ query, const float* __restrict__ enc,
    const float* __restrict__ W_s, const float* __restrict__ W_h,
    const float* __restrict__ Wout, const float* __restrict__ Woutb,
    float* __restrict__ EWS, float* __restrict__ EWHT,
    float* __restrict__ ENCW, float* __restrict__ QW2) {
  __shared__ __align__(16) float lds_w[64 * 132];   // 33.8 KB: one col-half
  __shared__ __align__(16) float lds_x[32 * 132];   // 16.9 KB; reused 64x33
  const int set = blockIdx.x >> 8;
  const int blk = blockIdx.x & 255;
  const int rb = blk >> 1, ch = blk & 1;
  const int r0 = rb * 32, c0 = ch * 64;
  const int tid = threadIdx.x;
  const float* in = (set == 1 || set == 2) ? enc : query;
  const float* Wb; int wst;
  if (set == 0)      { Wb = W_s;        wst = 128; }
  else if (set == 1) { Wb = W_h;        wst = 128; }
  else if (set == 2) { Wb = Wout;       wst = 256; }
  else               { Wb = Wout + 128; wst = 256; }
  for (int i = tid; i < 2048; i += 256) {           // W: 64 rows x 32 float4
    int r = i >> 5, c4 = i & 31;
    *(float4*)(lds_w + r * 132 + c4 * 4) =
        *(const float4*)(Wb + (c0 + r) * wst + c4 * 4);
  }
  for (int i = tid; i < 1024; i += 256) {           // x: 32 rows x 32 float4
    int r = i >> 5, c4 = i & 31;
    *(float4*)(lds_x + r * 132 + c4 * 4) =
        *(const float4*)(in + (r0 + r) * NH + c4 * 4);
  }
  __syncthreads();
  const int cg = tid & 31;         // cols c0+cg, c0+cg+32
  const int rg = tid >> 5;         // rows rg*4 .. rg*4+3
  float acc[4][2] = {{0,0},{0,0},{0,0},{0,0}};
  for (int k4 = 0; k4 < 32; ++k4) {
    float4 xa[4], wb[2];
    #pragma unroll
    for (int i = 0; i < 4; ++i)      // wave-uniform addr -> broadcast
      xa[i] = *(const float4*)(lds_x + (rg * 4 + i) * 132 + k4 * 4);
    #pragma unroll
    for (int m = 0; m < 2; ++m)      // bank = (cg+k4)%32 -> conflict-free
      wb[m] = *(const float4*)(lds_w + (cg + 32 * m) * 132 + k4 * 4);
    #pragma unroll
    for (int i = 0; i < 4; ++i)
      #pragma unroll
      for (int m = 0; m < 2; ++m)
        acc[i][m] += dot4(xa[i], wb[m]);
  }
  if (set == 0) {
    #pragma unroll
    for (int i = 0; i < 4; ++i)
      #pragma unroll
      for (int m = 0; m < 2; ++m)    // lanes cg consecutive -> coalesced
        EWS[(r0 + rg * 4 + i) * NH + c0 + cg + 32 * m] =
            fast_exp2(C2LOG2E * acc[i][m]);
  } else if (set == 1) {
    __syncthreads();                 // lds_x dead; reuse as 64x33 transpose
    #pragma unroll
    for (int i = 0; i < 4; ++i)
      #pragma unroll
      for (int m = 0; m < 2; ++m)
        lds_x[(cg + 32 * m) * 33 + rg * 4 + i] = fast_exp2(C2LOG2E * acc[i][m]);
    __syncthreads();
    const int b = r0 >> 9, sl0 = r0 & 511;
    const int s_lane = tid & 31, hr = tid >> 5;   // 8 groups x 8 h-rows
    #pragma unroll
    for (int j = 0; j < 8; ++j)      // lanes s consecutive -> coalesced 128B
      EWHT[b * NH * NS + (c0 + hr * 8 + j) * NS + sl0 + s_lane] =
          lds_x[(hr * 8 + j) * 33 + s_lane];
  } else if (set == 2) {
    #pragma unroll
    for (int i = 0; i < 4; ++i)
      #pragma unroll
      for (int m = 0; m < 2; ++m)
        ENCW[(r0 + rg * 4 + i) * NH + c0 + cg + 32 * m] = acc[i][m];
  } else {
    #pragma unroll
    for (int i = 0; i < 4; ++i)
      #pragma unroll
      for (int m = 0; m < 2; ++m) {
        int c = c0 + cg + 32 * m;    // bias folded here, not in mega
        QW2[(r0 + rg * 4 + i) * NH + c] = acc[i][m] + Woutb[c];
      }
  }
}

// -------- K2: MEGA (round-7 structure) — 512 thr, 8 t, grid 512 -----------
// Changes vs r7: (1) bb = blk&7 batch-interleave (per-CU load mixing),
// (2) LDS 55.3 -> 37.9 KB (s_par inside s_aT region; 3-stage D reduction in
//     s_sc region) -> 4 blocks/CU capacity, __launch_bounds__(512,8).
__global__ __launch_bounds__(512, 8) void bah_mega_kernel(
    const float* __restrict__ EWS, const float* __restrict__ EWHT,
    const float* __restrict__ v, const float* __restrict__ ENCW,
    const float* __restrict__ QW2, const int* __restrict__ src_len,
    float* __restrict__ out) {
  // Arena (floats), phase-aliased:
  //  A [0,4096)     s_par (B: [tt*512+2sp] float2) -> s_aT (C,D: [s*8+t])
  //  B [4096,8224)  s_sc (B->C: 8x516 scores) -> red4 (D: 4x1024 tree buf)
  //  C [8224,9280)  s_et (8x132)
  //  D [9280,9408)  s_v
  //  E [9408,9472)  s_red
  __shared__ __align__(16) float smem[9472];
  float* s_par = smem;
  float* s_aT  = smem;
  float* s_sc  = smem + 4096;
  float* red4  = smem + 4096;
  float* s_et  = smem + 8224;
  float* s_v   = smem + 9280;
  float* s_red = smem + 9408;

  const int tid = threadIdx.x;
  const int bb = blockIdx.x & 7;              // batch-interleave swizzle
  const int t0 = (blockIdx.x >> 3) * 8;
  const int len = src_len[bb];

  if (tid < 32) *(float4*)(s_v + tid * 4) = *(const float4*)(v + tid * 4);
  if (tid < 256) {                     // 8x128 EWS rows = 256 float4
    int r = tid >> 5, c4 = tid & 31;
    *(float4*)(s_et + r * 132 + c4 * 4) =
        *(const float4*)(EWS + (bb * NT + t0 + r) * NH + c4 * 4);
  }
  __syncthreads();

  // V0 = sum(v): one float2 + wave shuffles
  float V0;
  {
    float2 vv = *(const float2*)(s_v + (tid & 63) * 2);
    V0 = vv.x + vv.y;
    #pragma unroll
    for (int msk = 1; msk <= 32; msk <<= 1)
      V0 += __shfl_xor(V0, msk, 64);
  }

  // ---- Phase B: tg=tid>>8 (h-half), sp=tid&255 (2 contiguous s), 8 t ----
  const int tg = tid >> 8, sp = tid & 255;
  const int sbase = sp * 2;
  const int h0 = tg * 64;
  float2 acc2[8];
  #pragma unroll
  for (int i = 0; i < 8; ++i) { acc2[i].x = 0.f; acc2[i].y = 0.f; }
  const int wave_s0 = (sp & ~63) * 2;     // wave-uniform start of 128-s span
  if (wave_s0 < len) {                    // skip fully-masked span
    const float* fb = EWHT + bb * NH * NS + h0 * NS + sbase;
    for (int ho = 0; ho < 8; ++ho) {
      const float* fh = fb + ho * 8 * NS;
      float2 F0 = *(const float2*)(fh + 0 * NS);   // coalesced 8B/lane (L2)
      float2 F1 = *(const float2*)(fh + 1 * NS);
      float2 F2 = *(const float2*)(fh + 2 * NS);
      float2 F3 = *(const float2*)(fh + 3 * NS);
      float2 F4 = *(const float2*)(fh + 4 * NS);
      float2 F5 = *(const float2*)(fh + 5 * NS);
      float2 F6 = *(const float2*)(fh + 6 * NS);
      float2 F7 = *(const float2*)(fh + 7 * NS);
      float4 va = *(const float4*)(s_v + h0 + ho * 8);
      float4 vb = *(const float4*)(s_v + h0 + ho * 8 + 4);
      #pragma unroll
      for (int tt = 0; tt < 8; ++tt) {
        float4 e0 = *(const float4*)(s_et + tt * 132 + h0 + ho * 8);  // bcast
        float4 e1 = *(const float4*)(s_et + tt * 132 + h0 + ho * 8 + 4);
        acc2[tt] = pair_acc2(e0.x, e0.y, va.x, va.y, F0, F1, acc2[tt]);
        acc2[tt] = pair_acc2(e0.z, e0.w, va.z, va.w, F2, F3, acc2[tt]);
        acc2[tt] = pair_acc2(e1.x, e1.y, vb.x, vb.y, F4, F5, acc2[tt]);
        acc2[tt] = pair_acc2(e1.z, e1.w, vb.z, vb.w, F6, F7, acc2[tt]);
      }
    }
  }
  if (tg == 1) {                       // b64 stride-1 per tt: 2-way, free
    #pragma unroll
    for (int tt = 0; tt < 8; ++tt)
      *(float2*)(s_par + tt * 512 + sp * 2) = acc2[tt];
  }
  __syncthreads();
  if (tg == 0) {
    #pragma unroll
    for (int tt = 0; tt < 8; ++tt) {
      float2 oth = *(const float2*)(s_par + tt * 512 + sp * 2);
      float sx = acc2[tt].x + oth.x;
      float sy = acc2[tt].y + oth.y;
      float2 r;  // faithful quirk: masked scores ZEROED, still in softmax
      r.x = (sbase + 0 < len) ? fmaf(-2.f, sx, V0) : 0.f;
      r.y = (sbase + 1 < len) ? fmaf(-2.f, sy, V0) : 0.f;
      *(float2*)(s_sc + tt * 516 + sbase) = r;
    }
  }
  __syncthreads();

  // ---- Phase C: softmax per t-row; attn transposed into s_aT ----
  // (s_aT overlays s_par — dead after the combine above; writes happen
  //  only after the final sum barrier below.)
  const int t = tid & 7;
  const int c = tid >> 3;       // 0..63, 8 strided s values each
  const int wv = tid >> 6;
  float pv[8];
  float mx = -3.4e38f;
  #pragma unroll
  for (int k = 0; k < 8; ++k) {
    pv[k] = s_sc[t * 516 + c + 64 * k];
    mx = fmaxf(mx, pv[k]);
  }
  #pragma unroll
  for (int msk = 8; msk <= 32; msk <<= 1)
    mx = fmaxf(mx, __shfl_xor(mx, msk, 64));
  if ((tid & 63) < 8) s_red[wv * 8 + t] = mx;
  __syncthreads();
  #pragma unroll
  for (int j = 1; j < 8; ++j) mx = fmaxf(mx, s_red[j * 8 + t]);
  mx = fmaxf(mx, s_red[t]);
  __syncthreads();              // reads done before s_red rewrite
  float sum = 0.f;
  #pragma unroll
  for (int k = 0; k < 8; ++k) {
    pv[k] = fast_exp2((pv[k] - mx) * 1.4426950408889634f);
    sum += pv[k];
  }
  #pragma unroll
  for (int msk = 8; msk <= 32; msk <<= 1)
    sum += __shfl_xor(sum, msk, 64);
  if ((tid & 63) < 8) s_red[wv * 8 + t] = sum;
  __syncthreads();
  sum = 0.f;
  #pragma unroll
  for (int j = 0; j < 8; ++j) sum += s_red[j * 8 + t];
  const float rd = fast_rcp(sum);
  #pragma unroll
  for (int k = 0; k < 8; ++k)   // word 8(c+64k)+t = tid+512k: stride-1
    s_aT[(c + 64 * k) * 8 + t] = pv[k] * rd;
  __syncthreads();

  // ---- Phase D: pre_out[t][c] = sum_s attn[t][s]*ENCW[s][c]; +QW2; tanh --
  const int hg = tid & 31, sg = tid >> 5;   // 16 s-groups x 32 s
  float4 a8[8] = {{0,0,0,0},{0,0,0,0},{0,0,0,0},{0,0,0,0},
                  {0,0,0,0},{0,0,0,0},{0,0,0,0},{0,0,0,0}};
  const float* eb = ENCW + bb * NS * NH + hg * 4;
  for (int k = 0; k < 32; ++k) {
    int s = sg * 32 + k;
    float4 e  = *(const float4*)(eb + s * NH);      // coalesced global
    float4 w0 = *(const float4*)(s_aT + s * 8);     // 2 addrs/wave: free
    float4 w1 = *(const float4*)(s_aT + s * 8 + 4);
    a8[0].x += w0.x*e.x; a8[0].y += w0.x*e.y; a8[0].z += w0.x*e.z; a8[0].w += w0.x*e.w;
    a8[1].x += w0.y*e.x; a8[1].y += w0.y*e.y; a8[1].z += w0.y*e.z; a8[1].w += w0.y*e.w;
    a8[2].x += w0.z*e.x; a8[2].y += w0.z*e.y; a8[2].z += w0.z*e.z; a8[2].w += w0.z*e.w;
    a8[3].x += w0.w*e.x; a8[3].y += w0.w*e.y; a8[3].z += w0.w*e.z; a8[3].w += w0.w*e.w;
    a8[4].x += w1.x*e.x; a8[4].y += w1.x*e.y; a8[4].z += w1.x*e.z; a8[4].w += w1.x*e.w;
    a8[5].x += w1.y*e.x; a8[5].y += w1.y*e.y; a8[5].z += w1.y*e.z; a8[5].w += w1.y*e.w;
    a8[6].x += w1.z*e.x; a8[6].y += w1.z*e.y; a8[6].z += w1.z*e.z; a8[6].w += w1.z*e.w;
    a8[7].x += w1.w*e.x; a8[7].y += w1.w*e.y; a8[7].z += w1.w*e.z; a8[7].w += w1.w*e.w;
  }
  #pragma unroll
  for (int i = 0; i < 8; ++i) {     // sg pairs within wave (lane^32)
    a8[i].x += __shfl_xor(a8[i].x, 32, 64);
    a8[i].y += __shfl_xor(a8[i].y, 32, 64);
    a8[i].z += __shfl_xor(a8[i].z, 32, 64);
    a8[i].w += __shfl_xor(a8[i].w, 32, 64);
  }
  // 3-stage cross-wave tree (8->4->2->1) inside red4 (s_sc region, 4128 fl).
  const int lane = tid & 63;
  const bool lo = lane < 32;
  if (wv >= 4 && lo) {                        // stage 1: waves 4-7 publish
    #pragma unroll
    for (int i = 0; i < 8; ++i)
      *(float4*)(red4 + (wv - 4) * 1024 + i * 128 + hg * 4) = a8[i];
  }
  __syncthreads();
  if (wv < 4 && lo) {
    #pragma unroll
    for (int i = 0; i < 8; ++i) {
      float4 p = *(const float4*)(red4 + wv * 1024 + i * 128 + hg * 4);
      a8[i].x += p.x; a8[i].y += p.y; a8[i].z += p.z; a8[i].w += p.w;
    }
  }
  __syncthreads();
  if (wv >= 2 && wv < 4 && lo) {              // stage 2: waves 2-3 publish
    #pragma unroll
    for (int i = 0; i < 8; ++i)
      *(float4*)(red4 + (wv - 2) * 1024 + i * 128 + hg * 4) = a8[i];
  }
  __syncthreads();
  if (wv < 2 && lo) {
    #pragma unroll
    for (int i = 0; i < 8; ++i) {
      float4 p = *(const float4*)(red4 + wv * 1024 + i * 128 + hg * 4);
      a8[i].x += p.x; a8[i].y += p.y; a8[i].z += p.z; a8[i].w += p.w;
    }
  }
  __syncthreads();
  if (wv == 1 && lo) {                        // stage 3: wave 1 publishes
    #pragma unroll
    for (int i = 0; i < 8; ++i)
      *(float4*)(red4 + i * 128 + hg * 4) = a8[i];
  }
  __syncthreads();
  if (wv == 0 && lo) {                        // wave 0: final + QW2 + tanh
    #pragma unroll
    for (int i = 0; i < 8; ++i) {
      float4 p = *(const float4*)(red4 + i * 128 + hg * 4);
      const int row = bb * NT + t0 + i;
      float4 q4 = *(const float4*)(QW2 + row * NH + hg * 4);
      float4 r;
      r.x = fast_tanh(a8[i].x + p.x + q4.x);
      r.y = fast_tanh(a8[i].y + p.y + q4.y);
      r.z = fast_tanh(a8[i].z + p.z + q4.z);
      r.w = fast_tanh(a8[i].w + p.w + q4.w);
      *(float4*)(out + row * NH + hg * 4) = r;
    }
  }
}

extern "C" void kernel_launch(void* const* d_in, const int* in_sizes, int n_in,
                              void* d_out, int out_size, void* d_ws, size_t ws_size,
                              hipStream_t stream) {
  const float* query = (const float*)d_in[0];
  const float* enc   = (const float*)d_in[1];
  const int*   slen  = (const int*)d_in[2];
  const float* W_h   = (const float*)d_in[3];
  const float* W_s   = (const float*)d_in[4];
  const float* v     = (const float*)d_in[5];
  const float* Woutw = (const float*)d_in[6];
  const float* Woutb = (const float*)d_in[7];
  float* out = (float*)d_out;

  float* ws = (float*)d_ws;
  float* EWS  = ws;                  // B*T*H (2 MB)
  float* EWHT = ws + 524288;         // B*H*S transposed (2 MB)
  float* ENCW = ws + 1048576;        // B*S*H = enc @ W1^T (2 MB)
  float* QW2  = ws + 1572864;        // B*T*H = q @ W2^T + bias (2 MB)

  bah_proj_kernel<<<1024, 256, 0, stream>>>(query, enc, W_s, W_h, Woutw,
                                            Woutb, EWS, EWHT, ENCW, QW2);
  bah_mega_kernel<<<512, 512, 0, stream>>>(EWS, EWHT, v, ENCW, QW2, slen, out);
}

// Round 10
// 118.602 us; speedup vs baseline: 1.0947x; 1.0669x over previous
//
#include <hip/hip_runtime.h>

#define NB 8
#define NT 512
#define NS 512
#define NH 128
#define C2LOG2E 2.8853900817779268f   // 2*log2(e): exp2(C*x) = e^(2x)

__device__ __forceinline__ float fast_exp2(float x) { return __builtin_amdgcn_exp2f(x); }
__device__ __forceinline__ float fast_rcp(float x)  { return __builtin_amdgcn_rcpf(x); }
__device__ __forceinline__ float fast_tanh(float x) {
  float e = fast_exp2(x * C2LOG2E);
  return 1.0f - 2.0f * fast_rcp(e + 1.0f);
}

__device__ __forceinline__ float dot4(float4 a, float4 b) {
  return (a.x * b.x + a.y * b.y) + (a.z * b.z + a.w * b.w);
}

// acc += v0/(e0*f0+1) + v1/(e1*f1+1) over 2 s values; 1 rcp per 2 h-elems.
__device__ __forceinline__ float2 pair_acc2(float e0, float e1, float v0, float v1,
                                            float2 f0, float2 f1, float2 acc) {
  float2 P0, P1, num, den;
  P0.x = fmaf(e0, f0.x, 1.0f); P0.y = fmaf(e0, f0.y, 1.0f);
  P1.x = fmaf(e1, f1.x, 1.0f); P1.y = fmaf(e1, f1.y, 1.0f);
  num.x = fmaf(v0, P1.x, v1 * P0.x); num.y = fmaf(v0, P1.y, v1 * P0.y);
  den.x = P0.x * P1.x; den.y = P0.y * P1.y;
  acc.x = fmaf(num.x, fast_rcp(den.x), acc.x);
  acc.y = fmaf(num.y, fast_rcp(den.y), acc.y);
  return acc;
}

// ---------------- K1: four 4096x128x128 GEMMs (round-7, proven) -----------
// set 0: EWS  = exp2(C*(q  @ W_s^T))            [b][t][h]
// set 1: EWHT = exp2(C*(enc@ W_h^T)) TRANSPOSED [b][h][s]
// set 2: ENCW = enc @ W1^T   (W1 = Wout[:, :128])        [b][s][c]
// set 3: QW2  = q @ W2^T + b (W2 = Wout[:, 128:])        [b][t][c]
__global__ __launch_bounds__(256) void bah_proj_kernel(
    const float* __restrict__ query, const float* __restrict__ enc,
    const float* __restrict__ W_s, const float* __restrict__ W_h,
    const float* __restrict__ Wout, const float* __restrict__ Woutb,
    float* __restrict__ EWS, float* __restrict__ EWHT,
    float* __restrict__ ENCW, float* __restrict__ QW2) {
  __shared__ __align__(16) float lds_w[64 * 132];   // 33.8 KB: one col-half
  __shared__ __align__(16) float lds_x[32 * 132];   // 16.9 KB; reused 64x33
  const int set = blockIdx.x >> 8;
  const int blk = blockIdx.x & 255;
  const int rb = blk >> 1, ch = blk & 1;
  const int r0 = rb * 32, c0 = ch * 64;
  const int tid = threadIdx.x;
  const float* in = (set == 1 || set == 2) ? enc : query;
  const float* Wb; int wst;
  if (set == 0)      { Wb = W_s;        wst = 128; }
  else if (set == 1) { Wb = W_h;        wst = 128; }
  else if (set == 2) { Wb = Wout;       wst = 256; }
  else               { Wb = Wout + 128; wst = 256; }
  for (int i = tid; i < 2048; i += 256) {           // W: 64 rows x 32 float4
    int r = i >> 5, c4 = i & 31;
    *(float4*)(lds_w + r * 132 + c4 * 4) =
        *(const float4*)(Wb + (c0 + r) * wst + c4 * 4);
  }
  for (int i = tid; i < 1024; i += 256) {           // x: 32 rows x 32 float4
    int r = i >> 5, c4 = i & 31;
    *(float4*)(lds_x + r * 132 + c4 * 4) =
        *(const float4*)(in + (r0 + r) * NH + c4 * 4);
  }
  __syncthreads();
  const int cg = tid & 31;         // cols c0+cg, c0+cg+32
  const int rg = tid >> 5;         // rows rg*4 .. rg*4+3
  float acc[4][2] = {{0,0},{0,0},{0,0},{0,0}};
  for (int k4 = 0; k4 < 32; ++k4) {
    float4 xa[4], wb[2];
    #pragma unroll
    for (int i = 0; i < 4; ++i)      // wave-uniform addr -> broadcast
      xa[i] = *(const float4*)(lds_x + (rg * 4 + i) * 132 + k4 * 4);
    #pragma unroll
    for (int m = 0; m < 2; ++m)      // bank = (cg+k4)%32 -> conflict-free
      wb[m] = *(const float4*)(lds_w + (cg + 32 * m) * 132 + k4 * 4);
    #pragma unroll
    for (int i = 0; i < 4; ++i)
      #pragma unroll
      for (int m = 0; m < 2; ++m)
        acc[i][m] += dot4(xa[i], wb[m]);
  }
  if (set == 0) {
    #pragma unroll
    for (int i = 0; i < 4; ++i)
      #pragma unroll
      for (int m = 0; m < 2; ++m)    // lanes cg consecutive -> coalesced
        EWS[(r0 + rg * 4 + i) * NH + c0 + cg + 32 * m] =
            fast_exp2(C2LOG2E * acc[i][m]);
  } else if (set == 1) {
    __syncthreads();                 // lds_x dead; reuse as 64x33 transpose
    #pragma unroll
    for (int i = 0; i < 4; ++i)
      #pragma unroll
      for (int m = 0; m < 2; ++m)
        lds_x[(cg + 32 * m) * 33 + rg * 4 + i] = fast_exp2(C2LOG2E * acc[i][m]);
    __syncthreads();
    const int b = r0 >> 9, sl0 = r0 & 511;
    const int s_lane = tid & 31, hr = tid >> 5;   // 8 groups x 8 h-rows
    #pragma unroll
    for (int j = 0; j < 8; ++j)      // lanes s consecutive -> coalesced 128B
      EWHT[b * NH * NS + (c0 + hr * 8 + j) * NS + sl0 + s_lane] =
          lds_x[(hr * 8 + j) * 33 + s_lane];
  } else if (set == 2) {
    #pragma unroll
    for (int i = 0; i < 4; ++i)
      #pragma unroll
      for (int m = 0; m < 2; ++m)
        ENCW[(r0 + rg * 4 + i) * NH + c0 + cg + 32 * m] = acc[i][m];
  } else {
    #pragma unroll
    for (int i = 0; i < 4; ++i)
      #pragma unroll
      for (int m = 0; m < 2; ++m) {
        int c = c0 + cg + 32 * m;    // bias folded here, not in mega
        QW2[(r0 + rg * 4 + i) * NH + c] = acc[i][m] + Woutb[c];
      }
  }
}

// -------- K2: MEGA — 512 thr, 8 t, grid 512, 37.9 KB LDS ------------------
// bb = blk&7 batch-interleave (per-XCD L2 locality, FETCH 15.9->7.3 MB r9).
// NO min-waves in launch_bounds: r9's (512,8) capped VGPR at 32 and cost
// 15% VALU issue. Natural 52 VGPR allows 8 waves/SIMD; LDS 37.9 KB allows
// 4 blocks/CU -> 32 waves/CU without constraining the allocator.
__global__ __launch_bounds__(512) void bah_mega_kernel(
    const float* __restrict__ EWS, const float* __restrict__ EWHT,
    const float* __restrict__ v, const float* __restrict__ ENCW,
    const float* __restrict__ QW2, const int* __restrict__ src_len,
    float* __restrict__ out) {
  // Arena (floats), phase-aliased:
  //  A [0,4096)     s_par (B: [tt*512+2sp] float2) -> s_aT (C,D: [s*8+t])
  //  B [4096,8224)  s_sc (B->C: 8x516 scores) -> red4 (D: 4x1024 tree buf)
  //  C [8224,9280)  s_et (8x132)
  //  D [9280,9408)  s_v
  //  E [9408,9472)  s_red
  __shared__ __align__(16) float smem[9472];
  float* s_par = smem;
  float* s_aT  = smem;
  float* s_sc  = smem + 4096;
  float* red4  = smem + 4096;
  float* s_et  = smem + 8224;
  float* s_v   = smem + 9280;
  float* s_red = smem + 9408;

  const int tid = threadIdx.x;
  const int bb = blockIdx.x & 7;              // batch-interleave swizzle
  const int t0 = (blockIdx.x >> 3) * 8;
  const int len = src_len[bb];

  if (tid < 32) *(float4*)(s_v + tid * 4) = *(const float4*)(v + tid * 4);
  if (tid < 256) {                     // 8x128 EWS rows = 256 float4
    int r = tid >> 5, c4 = tid & 31;
    *(float4*)(s_et + r * 132 + c4 * 4) =
        *(const float4*)(EWS + (bb * NT + t0 + r) * NH + c4 * 4);
  }
  __syncthreads();

  // V0 = sum(v): one float2 + wave shuffles
  float V0;
  {
    float2 vv = *(const float2*)(s_v + (tid & 63) * 2);
    V0 = vv.x + vv.y;
    #pragma unroll
    for (int msk = 1; msk <= 32; msk <<= 1)
      V0 += __shfl_xor(V0, msk, 64);
  }

  // ---- Phase B: tg=tid>>8 (h-half), sp=tid&255 (2 contiguous s), 8 t ----
  const int tg = tid >> 8, sp = tid & 255;
  const int sbase = sp * 2;
  const int h0 = tg * 64;
  float2 acc2[8];
  #pragma unroll
  for (int i = 0; i < 8; ++i) { acc2[i].x = 0.f; acc2[i].y = 0.f; }
  const int wave_s0 = (sp & ~63) * 2;     // wave-uniform start of 128-s span
  if (wave_s0 < len) {                    // skip fully-masked span
    const float* fb = EWHT + bb * NH * NS + h0 * NS + sbase;
    for (int ho = 0; ho < 8; ++ho) {
      const float* fh = fb + ho * 8 * NS;
      float2 F0 = *(const float2*)(fh + 0 * NS);   // coalesced 8B/lane (L2)
      float2 F1 = *(const float2*)(fh + 1 * NS);
      float2 F2 = *(const float2*)(fh + 2 * NS);
      float2 F3 = *(const float2*)(fh + 3 * NS);
      float2 F4 = *(const float2*)(fh + 4 * NS);
      float2 F5 = *(const float2*)(fh + 5 * NS);
      float2 F6 = *(const float2*)(fh + 6 * NS);
      float2 F7 = *(const float2*)(fh + 7 * NS);
      float4 va = *(const float4*)(s_v + h0 + ho * 8);
      float4 vb = *(const float4*)(s_v + h0 + ho * 8 + 4);
      #pragma unroll
      for (int tt = 0; tt < 8; ++tt) {
        float4 e0 = *(const float4*)(s_et + tt * 132 + h0 + ho * 8);  // bcast
        float4 e1 = *(const float4*)(s_et + tt * 132 + h0 + ho * 8 + 4);
        acc2[tt] = pair_acc2(e0.x, e0.y, va.x, va.y, F0, F1, acc2[tt]);
        acc2[tt] = pair_acc2(e0.z, e0.w, va.z, va.w, F2, F3, acc2[tt]);
        acc2[tt] = pair_acc2(e1.x, e1.y, vb.x, vb.y, F4, F5, acc2[tt]);
        acc2[tt] = pair_acc2(e1.z, e1.w, vb.z, vb.w, F6, F7, acc2[tt]);
      }
    }
  }
  if (tg == 1) {                       // b64 stride-1 per tt: 2-way, free
    #pragma unroll
    for (int tt = 0; tt < 8; ++tt)
      *(float2*)(s_par + tt * 512 + sp * 2) = acc2[tt];
  }
  __syncthreads();
  if (tg == 0) {
    #pragma unroll
    for (int tt = 0; tt < 8; ++tt) {
      float2 oth = *(const float2*)(s_par + tt * 512 + sp * 2);
      float sx = acc2[tt].x + oth.x;
      float sy = acc2[tt].y + oth.y;
      float2 r;  // faithful quirk: masked scores ZEROED, still in softmax
      r.x = (sbase + 0 < len) ? fmaf(-2.f, sx, V0) : 0.f;
      r.y = (sbase + 1 < len) ? fmaf(-2.f, sy, V0) : 0.f;
      *(float2*)(s_sc + tt * 516 + sbase) = r;
    }
  }
  __syncthreads();

  // ---- Phase C: softmax per t-row; attn transposed into s_aT ----
  // (s_aT overlays s_par — dead after the combine above; writes happen
  //  only after the final sum barrier below.)
  const int t = tid & 7;
  const int c = tid >> 3;       // 0..63, 8 strided s values each
  const int wv = tid >> 6;
  float pv[8];
  float mx = -3.4e38f;
  #pragma unroll
  for (int k = 0; k < 8; ++k) {
    pv[k] = s_sc[t * 516 + c + 64 * k];
    mx = fmaxf(mx, pv[k]);
  }
  #pragma unroll
  for (int msk = 8; msk <= 32; msk <<= 1)
    mx = fmaxf(mx, __shfl_xor(mx, msk, 64));
  if ((tid & 63) < 8) s_red[wv * 8 + t] = mx;
  __syncthreads();
  #pragma unroll
  for (int j = 1; j < 8; ++j) mx = fmaxf(mx, s_red[j * 8 + t]);
  mx = fmaxf(mx, s_red[t]);
  __syncthreads();              // reads done before s_red rewrite
  float sum = 0.f;
  #pragma unroll
  for (int k = 0; k < 8; ++k) {
    pv[k] = fast_exp2((pv[k] - mx) * 1.4426950408889634f);
    sum += pv[k];
  }
  #pragma unroll
  for (int msk = 8; msk <= 32; msk <<= 1)
    sum += __shfl_xor(sum, msk, 64);
  if ((tid & 63) < 8) s_red[wv * 8 + t] = sum;
  __syncthreads();
  sum = 0.f;
  #pragma unroll
  for (int j = 0; j < 8; ++j) sum += s_red[j * 8 + t];
  const float rd = fast_rcp(sum);
  #pragma unroll
  for (int k = 0; k < 8; ++k)   // word 8(c+64k)+t = tid+512k: stride-1
    s_aT[(c + 64 * k) * 8 + t] = pv[k] * rd;
  __syncthreads();

  // ---- Phase D: pre_out[t][c] = sum_s attn[t][s]*ENCW[s][c]; +QW2; tanh --
  const int hg = tid & 31, sg = tid >> 5;   // 16 s-groups x 32 s
  float4 a8[8] = {{0,0,0,0},{0,0,0,0},{0,0,0,0},{0,0,0,0},
                  {0,0,0,0},{0,0,0,0},{0,0,0,0},{0,0,0,0}};
  const float* eb = ENCW + bb * NS * NH + hg * 4;
  for (int k = 0; k < 32; ++k) {
    int s = sg * 32 + k;
    float4 e  = *(const float4*)(eb + s * NH);      // coalesced global
    float4 w0 = *(const float4*)(s_aT + s * 8);     // 2 addrs/wave: free
    float4 w1 = *(const float4*)(s_aT + s * 8 + 4);
    a8[0].x += w0.x*e.x; a8[0].y += w0.x*e.y; a8[0].z += w0.x*e.z; a8[0].w += w0.x*e.w;
    a8[1].x += w0.y*e.x; a8[1].y += w0.y*e.y; a8[1].z += w0.y*e.z; a8[1].w += w0.y*e.w;
    a8[2].x += w0.z*e.x; a8[2].y += w0.z*e.y; a8[2].z += w0.z*e.z; a8[2].w += w0.z*e.w;
    a8[3].x += w0.w*e.x; a8[3].y += w0.w*e.y; a8[3].z += w0.w*e.z; a8[3].w += w0.w*e.w;
    a8[4].x += w1.x*e.x; a8[4].y += w1.x*e.y; a8[4].z += w1.x*e.z; a8[4].w += w1.x*e.w;
    a8[5].x += w1.y*e.x; a8[5].y += w1.y*e.y; a8[5].z += w1.y*e.z; a8[5].w += w1.y*e.w;
    a8[6].x += w1.z*e.x; a8[6].y += w1.z*e.y; a8[6].z += w1.z*e.z; a8[6].w += w1.z*e.w;
    a8[7].x += w1.w*e.x; a8[7].y += w1.w*e.y; a8[7].z += w1.w*e.z; a8[7].w += w1.w*e.w;
  }
  #pragma unroll
  for (int i = 0; i < 8; ++i) {     // sg pairs within wave (lane^32)
    a8[i].x += __shfl_xor(a8[i].x, 32, 64);
    a8[i].y += __shfl_xor(a8[i].y, 32, 64);
    a8[i].z += __shfl_xor(a8[i].z, 32, 64);
    a8[i].w += __shfl_xor(a8[i].w, 32, 64);
  }
  // 3-stage cross-wave tree (8->4->2->1) inside red4 (s_sc region, 4128 fl).
  const int lane = tid & 63;
  const bool lo = lane < 32;
  if (wv >= 4 && lo) {                        // stage 1: waves 4-7 publish
    #pragma unroll
    for (int i = 0; i < 8; ++i)
      *(float4*)(red4 + (wv - 4) * 1024 + i * 128 + hg * 4) = a8[i];
  }
  __syncthreads();
  if (wv < 4 && lo) {
    #pragma unroll
    for (int i = 0; i < 8; ++i) {
      float4 p = *(const float4*)(red4 + wv * 1024 + i * 128 + hg * 4);
      a8[i].x += p.x; a8[i].y += p.y; a8[i].z += p.z; a8[i].w += p.w;
    }
  }
  __syncthreads();
  if (wv >= 2 && wv < 4 && lo) {              // stage 2: waves 2-3 publish
    #pragma unroll
    for (int i = 0; i < 8; ++i)
      *(float4*)(red4 + (wv - 2) * 1024 + i * 128 + hg * 4) = a8[i];
  }
  __syncthreads();
  if (wv < 2 && lo) {
    #pragma unroll
    for (int i = 0; i < 8; ++i) {
      float4 p = *(const float4*)(red4 + wv * 1024 + i * 128 + hg * 4);
      a8[i].x += p.x; a8[i].y += p.y; a8[i].z += p.z; a8[i].w += p.w;
    }
  }
  __syncthreads();
  if (wv == 1 && lo) {                        // stage 3: wave 1 publishes
    #pragma unroll
    for (int i = 0; i < 8; ++i)
      *(float4*)(red4 + i * 128 + hg * 4) = a8[i];
  }
  __syncthreads();
  if (wv == 0 && lo) {                        // wave 0: final + QW2 + tanh
    #pragma unroll
    for (int i = 0; i < 8; ++i) {
      float4 p = *(const float4*)(red4 + i * 128 + hg * 4);
      const int row = bb * NT + t0 + i;
      float4 q4 = *(const float4*)(QW2 + row * NH + hg * 4);
      float4 r;
      r.x = fast_tanh(a8[i].x + p.x + q4.x);
      r.y = fast_tanh(a8[i].y + p.y + q4.y);
      r.z = fast_tanh(a8[i].z + p.z + q4.z);
      r.w = fast_tanh(a8[i].w + p.w + q4.w);
      *(float4*)(out + row * NH + hg * 4) = r;
    }
  }
}

extern "C" void kernel_launch(void* const* d_in, const int* in_sizes, int n_in,
                              void* d_out, int out_size, void* d_ws, size_t ws_size,
                              hipStream_t stream) {
  const float* query = (const float*)d_in[0];
  const float* enc   = (const float*)d_in[1];
  const int*   slen  = (const int*)d_in[2];
  const float* W_h   = (const float*)d_in[3];
  const float* W_s   = (const float*)d_in[4];
  const float* v     = (const float*)d_in[5];
  const float* Woutw = (const float*)d_in[6];
  const float* Woutb = (const float*)d_in[7];
  float* out = (float*)d_out;

  float* ws = (float*)d_ws;
  float* EWS  = ws;                  // B*T*H (2 MB)
  float* EWHT = ws + 524288;         // B*H*S transposed (2 MB)
  float* ENCW = ws + 1048576;        // B*S*H = enc @ W1^T (2 MB)
  float* QW2  = ws + 1572864;        // B*T*H = q @ W2^T + bias (2 MB)

  bah_proj_kernel<<<1024, 256, 0, stream>>>(query, enc, W_s, W_h, Woutw,
                                            Woutb, EWS, EWHT, ENCW, QW2);
  bah_mega_kernel<<<512, 512, 0, stream>>>(EWS, EWHT, v, ENCW, QW2, slen, out);
}